// Round 2
// baseline (987.462 us; speedup 1.0000x reference)
//
#include <hip/hip_runtime.h>
#include <hip/hip_bf16.h>
#include <math.h>

// ---------- types ----------
typedef __attribute__((ext_vector_type(8))) __bf16 bh8;   // MFMA A/B frag (4 VGPRs)
typedef __attribute__((ext_vector_type(4))) float  f4;    // MFMA C/D frag

#define NTOK   8192
#define DIM    1024
#define NEXP   8
#define HID2   4096   // 2*HID
#define HIDK   2048

// ws layout (bytes)
#define OFF_CNT    0          // 8 * int
#define OFF_PSUM   64         // 8 * float
#define OFF_OFFS   128        // 8 * int
#define OFF_ROWS   512        // 8*8192 int
#define OFF_GATES  (512+262144)
#define OFF_XBF    524800     // 8388608 shorts
#define OFF_G      (524800+16777216)   // (16384+256) x 2048 shorts

__device__ __forceinline__ unsigned short f2bf(float x){
    union { float f; unsigned u; } v; v.f = x;
    unsigned r = v.u + 0x7FFFu + ((v.u >> 16) & 1u);
    return (unsigned short)(r >> 16);
}
__device__ __forceinline__ unsigned pk2(float a, float b){
    return (unsigned)f2bf(a) | ((unsigned)f2bf(b) << 16);
}

// ---------- x fp32 -> bf16 ----------
__global__ void convert_x(const float* __restrict__ x, short* __restrict__ xbf){
    size_t i = ((size_t)blockIdx.x * 256 + threadIdx.x) * 8;
    const float4* s = (const float4*)(x + i);
    float4 a = s[0], b = s[1];
    uint4 u;
    u.x = pk2(a.x, a.y); u.y = pk2(a.z, a.w);
    u.z = pk2(b.x, b.y); u.w = pk2(b.z, b.w);
    *(uint4*)(xbf + i) = u;
}

// ---------- router: logits, softmax stats, top-2, expert lists ----------
__global__ void router(const float* __restrict__ x, const float* __restrict__ Wr,
                       const float* __restrict__ br,
                       int* cnt, float* psum, int* rows, float* gates){
    __shared__ float pP[8];
    int t = threadIdx.x, lane = t & 63, w = t >> 6;
    if (t < 8) pP[t] = 0.f;
    __syncthreads();
    int n0 = blockIdx.x * 32 + w * 8;
    for (int tk = 0; tk < 8; tk++){
        int n = n0 + tk;
        float acc[8] = {0.f,0.f,0.f,0.f,0.f,0.f,0.f,0.f};
        const float* xr = x + (size_t)n * DIM;
        for (int d = lane; d < DIM; d += 64){
            float xv = xr[d];
            const float* wrow = Wr + d * 8;
            #pragma unroll
            for (int e = 0; e < 8; e++) acc[e] += xv * wrow[e];
        }
        #pragma unroll
        for (int e = 0; e < 8; e++){
            float v = acc[e];
            v += __shfl_xor(v, 32); v += __shfl_xor(v, 16); v += __shfl_xor(v, 8);
            v += __shfl_xor(v, 4);  v += __shfl_xor(v, 2);  v += __shfl_xor(v, 1);
            acc[e] = v;
        }
        if (lane == 0){
            float l[8], ex[8];
            float m = -1e30f;
            #pragma unroll
            for (int e = 0; e < 8; e++){ l[e] = acc[e] + br[e]; m = fmaxf(m, l[e]); }
            float s = 0.f;
            #pragma unroll
            for (int e = 0; e < 8; e++){ ex[e] = expf(l[e] - m); s += ex[e]; }
            float inv = 1.f / s;
            #pragma unroll
            for (int e = 0; e < 8; e++) atomicAdd(&pP[e], ex[e] * inv);
            int i0 = 0; float v0 = l[0];
            #pragma unroll
            for (int e = 1; e < 8; e++) if (l[e] > v0){ v0 = l[e]; i0 = e; }
            int i1 = -1; float v1 = -1e30f;
            #pragma unroll
            for (int e = 0; e < 8; e++) if (e != i0 && l[e] > v1){ v1 = l[e]; i1 = e; }
            float s0 = 1.f / (1.f + expf(v1 - v0));
            float s1 = 1.f - s0;
            int p0 = atomicAdd(&cnt[i0], 1);
            rows[i0 * NTOK + p0] = n; gates[i0 * NTOK + p0] = s0;
            int p1 = atomicAdd(&cnt[i1], 1);
            rows[i1 * NTOK + p1] = n; gates[i1 * NTOK + p1] = s1;
        }
    }
    __syncthreads();
    if (t < 8) atomicAdd(&psum[t], pP[t]);
}

// ---------- prefix offsets + aux loss ----------
__global__ void finalize_aux(const int* cnt, const float* psum, int* offs, float* out_aux){
    if (threadIdx.x == 0){
        int off = 0; float aux = 0.f;
        for (int e = 0; e < 8; e++){
            offs[e] = off; off += cnt[e];
            aux += ((float)cnt[e] * (1.f/8192.f)) * (psum[e] * (1.f/8192.f));
        }
        out_aux[0] = 8.f * aux;
    }
}

// ---------- GEMM1: h = Xg @ W1[e] (+b1) ; g = silu(a)*b, bf16 ----------
// tile: 256 tokens x (128 a-cols paired with 128 b-cols). BK=32. 512 thr, 8 waves.
__global__ __launch_bounds__(512, 2) void gemm1(
    const short* __restrict__ xbf, const float* __restrict__ W1,
    const float* __restrict__ b1, const int* __restrict__ cnt,
    const int* __restrict__ offs, const int* __restrict__ rows,
    short* __restrict__ g)
{
    int e = blockIdx.z;
    int Me = cnt[e];
    int mbase = blockIdx.y << 8;
    if (mbase >= Me) return;
    int c0 = blockIdx.x << 7;

    __shared__ short As[256 * 40];     // stride 80B: frag reads 2-way (free)
    __shared__ short Bsa[128 * 56];    // stride 112B: writes conflict-free, reads 2-way
    __shared__ short Bsb[128 * 56];

    int t = threadIdx.x, lane = t & 63, w = t >> 6;
    int wr = w & 3, wc = w >> 2;

    const int* rowsE = rows + (e << 13) + mbase;
    int r0 = t >> 2, r1 = r0 + 128, pa = t & 3;
    int tok0 = (mbase + r0 < Me) ? rowsE[r0] : 0;
    int tok1 = (mbase + r1 < Me) ? rowsE[r1] : 0;
    const short* xs0 = xbf + ((size_t)tok0 << 10) + (pa << 3);
    const short* xs1 = xbf + ((size_t)tok1 << 10) + (pa << 3);
    short* asw0 = &As[r0 * 40 + (pa << 3)];
    short* asw1 = &As[r1 * 40 + (pa << 3)];

    int cc = t & 127, kb = (t >> 7) << 3;
    const float* bsa = W1 + ((size_t)e << 22) + ((size_t)kb << 12) + c0 + cc;
    const float* bsb = bsa + HIDK;
    short* baw = &Bsa[cc * 56 + kb];
    short* bbw = &Bsb[cc * 56 + kb];

    f4 acc_a[4][4], acc_b[4][4];
    f4 zz = {0.f, 0.f, 0.f, 0.f};
    #pragma unroll
    for (int i = 0; i < 4; i++)
        #pragma unroll
        for (int j = 0; j < 4; j++){ acc_a[i][j] = zz; acc_b[i][j] = zz; }

    int koff = (lane >> 4) << 3;   // quad*8: one 16x16x32 MFMA consumes full K=32

    for (int k0 = 0; k0 < DIM; k0 += 32){
        __syncthreads();
        *(uint4*)asw0 = *(const uint4*)(xs0 + k0);
        *(uint4*)asw1 = *(const uint4*)(xs1 + k0);
        {
            const float* p = bsa + ((size_t)k0 << 12);
            float a0 = p[0], a1 = p[4096], a2 = p[8192], a3 = p[12288];
            float a4 = p[16384], a5 = p[20480], a6 = p[24576], a7 = p[28672];
            uint4 u; u.x = pk2(a0,a1); u.y = pk2(a2,a3); u.z = pk2(a4,a5); u.w = pk2(a6,a7);
            *(uint4*)baw = u;
            const float* q = bsb + ((size_t)k0 << 12);
            float b0 = q[0], b1_ = q[4096], b2_ = q[8192], b3 = q[12288];
            float b4 = q[16384], b5 = q[20480], b6 = q[24576], b7 = q[28672];
            uint4 v; v.x = pk2(b0,b1_); v.y = pk2(b2_,b3); v.z = pk2(b4,b5); v.w = pk2(b6,b7);
            *(uint4*)bbw = v;
        }
        __syncthreads();
        bh8 av[4];
        #pragma unroll
        for (int i = 0; i < 4; i++)
            av[i] = *(const bh8*)&As[(wr*64 + i*16 + (lane & 15)) * 40 + koff];
        bh8 ba[4], bb[4];
        #pragma unroll
        for (int j = 0; j < 4; j++){
            int cb = wc*64 + j*16 + (lane & 15);
            ba[j] = *(const bh8*)&Bsa[cb * 56 + koff];
            bb[j] = *(const bh8*)&Bsb[cb * 56 + koff];
        }
        #pragma unroll
        for (int i = 0; i < 4; i++)
            #pragma unroll
            for (int j = 0; j < 4; j++){
                acc_a[i][j] = __builtin_amdgcn_mfma_f32_16x16x32_bf16(av[i], ba[j], acc_a[i][j], 0, 0, 0);
                acc_b[i][j] = __builtin_amdgcn_mfma_f32_16x16x32_bf16(av[i], bb[j], acc_b[i][j], 0, 0, 0);
            }
    }
    // epilogue: silu(a)*b -> g (bf16)
    const float* b1e = b1 + (e << 12);
    int colb = wc * 64 + (lane & 15);
    float vba[4], vbb[4];
    #pragma unroll
    for (int j = 0; j < 4; j++){
        vba[j] = b1e[c0 + colb + j*16];
        vbb[j] = b1e[HIDK + c0 + colb + j*16];
    }
    int rb = wr * 64 + ((lane >> 4) << 2);
    short* gE = g + ((size_t)(offs[e] + mbase)) * HIDK;
    #pragma unroll
    for (int i = 0; i < 4; i++)
        #pragma unroll
        for (int reg = 0; reg < 4; reg++){
            int mr = rb + i*16 + reg;
            if (mbase + mr < Me){
                short* grow = gE + (size_t)mr * HIDK + c0 + colb;
                #pragma unroll
                for (int j = 0; j < 4; j++){
                    float va = acc_a[i][j][reg] + vba[j];
                    float vb = acc_b[i][j][reg] + vbb[j];
                    float gv = va / (1.f + __expf(-va)) * vb;
                    grow[j*16] = (short)f2bf(gv);
                }
            }
        }
}

// ---------- GEMM2: out[token] += gate * (g @ W2[e] + b2) ----------
__global__ __launch_bounds__(512, 2) void gemm2(
    const short* __restrict__ g, const float* __restrict__ W2,
    const float* __restrict__ b2, const int* __restrict__ cnt,
    const int* __restrict__ offs, const int* __restrict__ rows,
    const float* __restrict__ gates, float* __restrict__ out)
{
    int e = blockIdx.z;
    int Me = cnt[e];
    int mbase = blockIdx.y << 8;
    if (mbase >= Me) return;
    int d0 = blockIdx.x << 7;

    __shared__ short As[256 * 40];
    __shared__ short Bs[128 * 56];

    int t = threadIdx.x, lane = t & 63, w = t >> 6;
    int wr = w & 3, wc = w >> 2;

    int r0 = t >> 2, r1 = r0 + 128, pa = t & 3;
    int gbase = offs[e] + mbase;
    const short* gs0 = g + ((size_t)(gbase + r0)) * HIDK + (pa << 3);
    const short* gs1 = g + ((size_t)(gbase + r1)) * HIDK + (pa << 3);
    short* asw0 = &As[r0 * 40 + (pa << 3)];
    short* asw1 = &As[r1 * 40 + (pa << 3)];

    int cc = t & 127, kb = (t >> 7) << 3;
    const float* bs = W2 + ((size_t)e << 21) + ((size_t)kb << 10) + d0 + cc;
    short* bw = &Bs[cc * 56 + kb];

    f4 acc[4][4];
    f4 zz = {0.f, 0.f, 0.f, 0.f};
    #pragma unroll
    for (int i = 0; i < 4; i++)
        #pragma unroll
        for (int j = 0; j < 4; j++) acc[i][j] = zz;

    int koff = (lane >> 4) << 3;

    for (int k0 = 0; k0 < HIDK; k0 += 32){
        __syncthreads();
        *(uint4*)asw0 = *(const uint4*)(gs0 + k0);
        *(uint4*)asw1 = *(const uint4*)(gs1 + k0);
        {
            const float* p = bs + ((size_t)k0 << 10);
            float a0 = p[0], a1 = p[1024], a2 = p[2048], a3 = p[3072];
            float a4 = p[4096], a5 = p[5120], a6 = p[6144], a7 = p[7168];
            uint4 u; u.x = pk2(a0,a1); u.y = pk2(a2,a3); u.z = pk2(a4,a5); u.w = pk2(a6,a7);
            *(uint4*)bw = u;
        }
        __syncthreads();
        bh8 av[4];
        #pragma unroll
        for (int i = 0; i < 4; i++)
            av[i] = *(const bh8*)&As[(wr*64 + i*16 + (lane & 15)) * 40 + koff];
        bh8 bv[4];
        #pragma unroll
        for (int j = 0; j < 4; j++)
            bv[j] = *(const bh8*)&Bs[(wc*64 + j*16 + (lane & 15)) * 56 + koff];
        #pragma unroll
        for (int i = 0; i < 4; i++)
            #pragma unroll
            for (int j = 0; j < 4; j++)
                acc[i][j] = __builtin_amdgcn_mfma_f32_16x16x32_bf16(av[i], bv[j], acc[i][j], 0, 0, 0);
    }
    const float* b2e = b2 + (e << 10);
    int colb = wc * 64 + (lane & 15);
    float vb2[4];
    #pragma unroll
    for (int j = 0; j < 4; j++) vb2[j] = b2e[d0 + colb + j*16];
    const int* rowsE = rows + (e << 13) + mbase;
    const float* gatesE = gates + (e << 13) + mbase;
    int rb = wr * 64 + ((lane >> 4) << 2);
    #pragma unroll
    for (int i = 0; i < 4; i++)
        #pragma unroll
        for (int reg = 0; reg < 4; reg++){
            int mr = rb + i*16 + reg;
            if (mbase + mr < Me){
                int token = rowsE[mr];
                float gate = gatesE[mr];
                float* orow = out + ((size_t)token << 10) + d0 + colb;
                #pragma unroll
                for (int j = 0; j < 4; j++)
                    unsafeAtomicAdd(&orow[j*16], gate * (acc[i][j][reg] + vb2[j]));
            }
        }
}

extern "C" void kernel_launch(void* const* d_in, const int* in_sizes, int n_in,
                              void* d_out, int out_size, void* d_ws, size_t ws_size,
                              hipStream_t stream) {
    const float* x  = (const float*)d_in[0];
    const float* Wr = (const float*)d_in[1];
    const float* br = (const float*)d_in[2];
    const float* W1 = (const float*)d_in[3];
    const float* b1 = (const float*)d_in[4];
    const float* W2 = (const float*)d_in[5];
    const float* b2 = (const float*)d_in[6];
    float* out = (float*)d_out;

    char* ws = (char*)d_ws;
    int*   cnt   = (int*)(ws + OFF_CNT);
    float* psum  = (float*)(ws + OFF_PSUM);
    int*   offs  = (int*)(ws + OFF_OFFS);
    int*   rows  = (int*)(ws + OFF_ROWS);
    float* gates = (float*)(ws + OFF_GATES);
    short* xbf   = (short*)(ws + OFF_XBF);
    short* g     = (short*)(ws + OFF_G);

    hipMemsetAsync(ws, 0, 192, stream);                       // cnt + psum
    hipMemsetAsync(d_out, 0, (size_t)NTOK * DIM * 4, stream); // atomic target

    convert_x<<<4096, 256, 0, stream>>>(x, xbf);
    router<<<256, 256, 0, stream>>>(x, Wr, br, cnt, psum, rows, gates);
    finalize_aux<<<1, 64, 0, stream>>>(cnt, psum, offs, out + (size_t)NTOK * DIM);
    gemm1<<<dim3(16, 32, 8), 512, 0, stream>>>(xbf, W1, b1, cnt, offs, rows, g);
    gemm2<<<dim3(8, 32, 8), 512, 0, stream>>>(g, W2, b2, cnt, offs, rows, gates, out);
}

// Round 3
// 754.617 us; speedup vs baseline: 1.3086x; 1.3086x over previous
//
#include <hip/hip_runtime.h>
#include <hip/hip_bf16.h>
#include <math.h>

typedef __attribute__((ext_vector_type(8))) __bf16 bh8;   // MFMA A/B frag
typedef __attribute__((ext_vector_type(4))) float  f4;    // MFMA C/D frag

#define NTOK   8192
#define DIM    1024
#define HIDK   2048

// ws layout (bytes)
#define OFF_CNT    0
#define OFF_PSUM   64
#define OFF_OFFS   128
#define OFF_ROWS   512
#define OFF_GATES  (512+262144)
#define OFF_XBF    524800
#define OFF_G      (524800+16777216)          // 16640 x 2048 shorts
#define OFF_W1S    (OFF_G + 68157440)         // 8*4096*1024 shorts (swizzled blobs)
#define OFF_W2S    (OFF_W1S + 67108864)       // 8*1024*2048 shorts

__device__ __forceinline__ unsigned short f2bf(float x){
    union { float f; unsigned u; } v; v.f = x;
    unsigned r = v.u + 0x7FFFu + ((v.u >> 16) & 1u);
    return (unsigned short)(r >> 16);
}
__device__ __forceinline__ unsigned pk2(float a, float b){
    return (unsigned)f2bf(a) | ((unsigned)f2bf(b) << 16);
}
__device__ __forceinline__ void gload_lds16(const void* g, void* l){
    __builtin_amdgcn_global_load_lds((const __attribute__((address_space(1))) void*)g,
                                     (__attribute__((address_space(3))) void*)l, 16, 0, 0);
}

// ---------- x fp32 -> bf16 ----------
__global__ void convert_x(const float* __restrict__ x, short* __restrict__ xbf){
    size_t i = ((size_t)blockIdx.x * 256 + threadIdx.x) * 8;
    const float4* s = (const float4*)(x + i);
    float4 a = s[0], b = s[1];
    uint4 u;
    u.x = pk2(a.x, a.y); u.y = pk2(a.z, a.w);
    u.z = pk2(b.x, b.y); u.w = pk2(b.z, b.w);
    *(uint4*)(xbf + i) = u;
}

// ---------- weights: [e][K][N] fp32 -> swizzled bf16 blobs [e][N/128][K/32][4096 shorts] ----------
// blob slot s (16B) holds col nl=s>>2, k-chunk c = (s&3) ^ (nl&3) ^ ((nl>>2)&3), k = kb*32+c*8+0..7
__global__ void prep_w(const float* __restrict__ W, short* __restrict__ Ws,
                       int Kdim, int Ndim){
    int kb = blockIdx.x, nb = blockIdx.y, e = blockIdx.z;
    int KB = Kdim >> 5, NB = Ndim >> 7;
    __shared__ float tile[32 * 132];   // [k][n], pad 132
    int t = threadIdx.x;
    const float* src = W + ((size_t)(e * Kdim + kb * 32)) * Ndim + (size_t)nb * 128;
    #pragma unroll
    for (int l = 0; l < 4; l++){
        int flat = (l * 256 + t) * 4;
        int k = flat >> 7, n = flat & 127;
        float4 v = *(const float4*)(src + (size_t)k * Ndim + n);
        float* d = &tile[k * 132 + n];
        d[0] = v.x; d[1] = v.y; d[2] = v.z; d[3] = v.w;
    }
    __syncthreads();
    short* dst = Ws + (((size_t)(e * NB + nb)) * KB + kb) * 4096;
    uint out[8];
    #pragma unroll
    for (int sl = 0; sl < 2; sl++){
        int s = t * 2 + sl;
        int nl = s >> 2, pos = s & 3;
        int c = pos ^ (nl & 3) ^ ((nl >> 2) & 3);
        #pragma unroll
        for (int jj = 0; jj < 4; jj++){
            float a = tile[(c * 8 + jj * 2) * 132 + nl];
            float b = tile[(c * 8 + jj * 2 + 1) * 132 + nl];
            out[sl * 4 + jj] = pk2(a, b);
        }
    }
    *(uint4*)(dst + t * 16)     = *(uint4*)&out[0];
    *(uint4*)(dst + t * 16 + 8) = *(uint4*)&out[4];
}

// ---------- router: block-local lists, 8 global atomics/block ----------
__global__ void router(const float* __restrict__ x, const float* __restrict__ Wr,
                       const float* __restrict__ br,
                       int* cnt, float* psum, int* rows, float* gates){
    __shared__ float pP[8];
    __shared__ int   tE[32][2];
    __shared__ float tS[32][2];
    __shared__ int   lcnt[8], lpos[64], lexp[64], gbase[8];
    int t = threadIdx.x, lane = t & 63, w = t >> 6;
    if (t < 8){ pP[t] = 0.f; lcnt[t] = 0; }
    __syncthreads();
    int n0 = blockIdx.x * 32 + w * 8;
    for (int tk = 0; tk < 8; tk++){
        int n = n0 + tk;
        float acc[8] = {0,0,0,0,0,0,0,0};
        const float* xr = x + (size_t)n * DIM;
        for (int d = lane; d < DIM; d += 64){
            float xv = xr[d];
            const float* wrow = Wr + d * 8;
            #pragma unroll
            for (int e = 0; e < 8; e++) acc[e] += xv * wrow[e];
        }
        #pragma unroll
        for (int e = 0; e < 8; e++){
            float v = acc[e];
            v += __shfl_xor(v, 32); v += __shfl_xor(v, 16); v += __shfl_xor(v, 8);
            v += __shfl_xor(v, 4);  v += __shfl_xor(v, 2);  v += __shfl_xor(v, 1);
            acc[e] = v;
        }
        if (lane == 0){
            float l[8], ex[8], m = -1e30f;
            #pragma unroll
            for (int e = 0; e < 8; e++){ l[e] = acc[e] + br[e]; m = fmaxf(m, l[e]); }
            float s = 0.f;
            #pragma unroll
            for (int e = 0; e < 8; e++){ ex[e] = expf(l[e] - m); s += ex[e]; }
            float inv = 1.f / s;
            #pragma unroll
            for (int e = 0; e < 8; e++) atomicAdd(&pP[e], ex[e] * inv);
            int i0 = 0; float v0 = l[0];
            #pragma unroll
            for (int e = 1; e < 8; e++) if (l[e] > v0){ v0 = l[e]; i0 = e; }
            int i1 = -1; float v1 = -1e30f;
            #pragma unroll
            for (int e = 0; e < 8; e++) if (e != i0 && l[e] > v1){ v1 = l[e]; i1 = e; }
            float s0 = 1.f / (1.f + expf(v1 - v0));
            int ti = w * 8 + tk;
            tE[ti][0] = i0; tE[ti][1] = i1;
            tS[ti][0] = s0; tS[ti][1] = 1.f - s0;
        }
    }
    __syncthreads();
    if (t < 64){
        int e = tE[t >> 1][t & 1];
        lexp[t] = e;
        lpos[t] = atomicAdd(&lcnt[e], 1);
    }
    __syncthreads();
    if (t < 8){
        gbase[t] = atomicAdd(&cnt[t], lcnt[t]);
        atomicAdd(&psum[t], pP[t]);
    }
    __syncthreads();
    if (t < 64){
        int e = lexp[t];
        int p = gbase[e] + lpos[t];
        int n = blockIdx.x * 32 + (t >> 1);
        rows[e * NTOK + p]  = n;
        gates[e * NTOK + p] = tS[t >> 1][t & 1];
    }
}

__global__ void finalize_aux(const int* cnt, const float* psum, int* offs, float* out_aux){
    if (threadIdx.x == 0){
        int off = 0; float aux = 0.f;
        for (int e = 0; e < 8; e++){
            offs[e] = off; off += cnt[e];
            aux += ((float)cnt[e] * (1.f/8192.f)) * (psum[e] * (1.f/8192.f));
        }
        out_aux[0] = 8.f * aux;
    }
}

// ---------- GEMM1: g = silu(X W1a + b1a) * (X W1b + b1b), bf16 out ----------
// 256 rows x 128 g-cols per block (a-half + b-half). BK=32, 512 thr, async staging.
__global__ __launch_bounds__(512, 2) void gemm1(
    const short* __restrict__ xbf, const short* __restrict__ W1s,
    const float* __restrict__ b1, const int* __restrict__ cnt,
    const int* __restrict__ offs, const int* __restrict__ rows,
    short* __restrict__ g)
{
    int e = blockIdx.z;
    int Me = cnt[e];
    int mbase = blockIdx.y << 8;
    if (mbase >= Me) return;
    int nb = blockIdx.x;                 // 0..15 -> g cols nb*128
    __shared__ short As[256 * 32];       // 16KB swizzled
    __shared__ short Bsa[128 * 32];      // 8KB
    __shared__ short Bsb[128 * 32];      // 8KB

    int t = threadIdx.x, lane = t & 63, w = t >> 6;
    int wr = w & 3, wc = w >> 2;
    int m = lane & 15, q = lane >> 4;
    int sw8 = (q ^ (m & 3) ^ ((m >> 2) & 3)) << 3;   // swizzle offset in shorts

    // A gather (slot t covers row t>>2 chunk swizzled; + row+128 for second half)
    const int* rowsE = rows + (e << 13) + mbase;
    int r  = t >> 2, pos = t & 3;
    int ca = pos ^ (r & 3) ^ ((r >> 2) & 3);
    int r2 = r + 128;
    int tok0 = (mbase + r  < Me) ? rowsE[r]  : 0;
    int tok1 = (mbase + r2 < Me) ? rowsE[r2] : 0;
    const short* ga0 = xbf + ((size_t)tok0 << 10) + (ca << 3);
    const short* ga1 = xbf + ((size_t)tok1 << 10) + (ca << 3);
    const short* gb0 = W1s + (((size_t)(e * 32 + nb))      << 5) * 4096 + t * 8;
    const short* gb1 = W1s + (((size_t)(e * 32 + 16 + nb)) << 5) * 4096 + t * 8;
    short* ldsA0 = As  + w * 512;
    short* ldsA1 = As  + 4096 + w * 512;
    short* ldsBa = Bsa + w * 512;
    short* ldsBb = Bsb + w * 512;

    f4 acc_a[4][4], acc_b[4][4];
    f4 zz = {0.f,0.f,0.f,0.f};
    #pragma unroll
    for (int i = 0; i < 4; i++)
        #pragma unroll
        for (int j = 0; j < 4; j++){ acc_a[i][j] = zz; acc_b[i][j] = zz; }

    for (int k0 = 0; k0 < DIM; k0 += 32){
        __syncthreads();
        gload_lds16(ga0, ldsA0);
        gload_lds16(ga1, ldsA1);
        gload_lds16(gb0, ldsBa);
        gload_lds16(gb1, ldsBb);
        ga0 += 32; ga1 += 32; gb0 += 4096; gb1 += 4096;
        __syncthreads();
        bh8 av[4], ba[4], bb[4];
        #pragma unroll
        for (int i = 0; i < 4; i++)
            av[i] = *(const bh8*)&As[(wr*64 + i*16 + m) * 32 + sw8];
        #pragma unroll
        for (int j = 0; j < 4; j++){
            int nn = (wc*64 + j*16 + m) * 32 + sw8;
            ba[j] = *(const bh8*)&Bsa[nn];
            bb[j] = *(const bh8*)&Bsb[nn];
        }
        #pragma unroll
        for (int i = 0; i < 4; i++)
            #pragma unroll
            for (int j = 0; j < 4; j++){
                acc_a[i][j] = __builtin_amdgcn_mfma_f32_16x16x32_bf16(av[i], ba[j], acc_a[i][j], 0, 0, 0);
                acc_b[i][j] = __builtin_amdgcn_mfma_f32_16x16x32_bf16(av[i], bb[j], acc_b[i][j], 0, 0, 0);
            }
    }
    int c0 = nb << 7;
    const float* b1e = b1 + (e << 12);
    int colb = wc * 64 + m;
    float vba[4], vbb[4];
    #pragma unroll
    for (int j = 0; j < 4; j++){
        vba[j] = b1e[c0 + colb + j*16];
        vbb[j] = b1e[HIDK + c0 + colb + j*16];
    }
    int rb = wr * 64 + (q << 2);
    short* gE = g + ((size_t)(offs[e] + mbase)) * HIDK;
    #pragma unroll
    for (int i = 0; i < 4; i++)
        #pragma unroll
        for (int reg = 0; reg < 4; reg++){
            int mr = rb + i*16 + reg;
            if (mbase + mr < Me){
                short* grow = gE + (size_t)mr * HIDK + c0 + colb;
                #pragma unroll
                for (int j = 0; j < 4; j++){
                    float va = acc_a[i][j][reg] + vba[j];
                    float vb = acc_b[i][j][reg] + vbb[j];
                    grow[j*16] = (short)f2bf(va / (1.f + __expf(-va)) * vb);
                }
            }
        }
}

// ---------- GEMM2: out[token] += gate * (g W2 + b2) ----------
__global__ __launch_bounds__(512, 2) void gemm2(
    const short* __restrict__ g, const short* __restrict__ W2s,
    const float* __restrict__ b2, const int* __restrict__ cnt,
    const int* __restrict__ offs, const int* __restrict__ rows,
    const float* __restrict__ gates, float* __restrict__ out)
{
    int e = blockIdx.z;
    int Me = cnt[e];
    int mbase = blockIdx.y << 8;
    if (mbase >= Me) return;
    int db = blockIdx.x;                 // 0..7
    __shared__ short As[256 * 32];
    __shared__ short Bs[128 * 32];

    int t = threadIdx.x, lane = t & 63, w = t >> 6;
    int wr = w & 3, wc = w >> 2;
    int m = lane & 15, q = lane >> 4;
    int sw8 = (q ^ (m & 3) ^ ((m >> 2) & 3)) << 3;

    int gbaseR = offs[e] + mbase;
    int r  = t >> 2, pos = t & 3;
    int ca = pos ^ (r & 3) ^ ((r >> 2) & 3);
    const short* ga0 = g + ((size_t)(gbaseR + r))       * HIDK + (ca << 3);
    const short* ga1 = g + ((size_t)(gbaseR + r + 128)) * HIDK + (ca << 3);
    const short* gb0 = W2s + (((size_t)(e * 8 + db)) << 6) * 4096 + t * 8;
    short* ldsA0 = As + w * 512;
    short* ldsA1 = As + 4096 + w * 512;
    short* ldsB  = Bs + w * 512;

    f4 acc[4][4];
    f4 zz = {0.f,0.f,0.f,0.f};
    #pragma unroll
    for (int i = 0; i < 4; i++)
        #pragma unroll
        for (int j = 0; j < 4; j++) acc[i][j] = zz;

    for (int k0 = 0; k0 < HIDK; k0 += 32){
        __syncthreads();
        gload_lds16(ga0, ldsA0);
        gload_lds16(ga1, ldsA1);
        gload_lds16(gb0, ldsB);
        ga0 += 32; ga1 += 32; gb0 += 4096;
        __syncthreads();
        bh8 av[4], bv[4];
        #pragma unroll
        for (int i = 0; i < 4; i++)
            av[i] = *(const bh8*)&As[(wr*64 + i*16 + m) * 32 + sw8];
        #pragma unroll
        for (int j = 0; j < 4; j++)
            bv[j] = *(const bh8*)&Bs[(wc*64 + j*16 + m) * 32 + sw8];
        #pragma unroll
        for (int i = 0; i < 4; i++)
            #pragma unroll
            for (int j = 0; j < 4; j++)
                acc[i][j] = __builtin_amdgcn_mfma_f32_16x16x32_bf16(av[i], bv[j], acc[i][j], 0, 0, 0);
    }
    int d0 = db << 7;
    const float* b2e = b2 + (e << 10);
    int colb = wc * 64 + m;
    float vb2[4];
    #pragma unroll
    for (int j = 0; j < 4; j++) vb2[j] = b2e[d0 + colb + j*16];
    const int* rowsE = rows + (e << 13) + mbase;
    const float* gatesE = gates + (e << 13) + mbase;
    int rb = wr * 64 + (q << 2);
    #pragma unroll
    for (int i = 0; i < 4; i++)
        #pragma unroll
        for (int reg = 0; reg < 4; reg++){
            int mr = rb + i*16 + reg;
            if (mbase + mr < Me){
                int token = rowsE[mr];
                float gate = gatesE[mr];
                float* orow = out + ((size_t)token << 10) + d0 + colb;
                #pragma unroll
                for (int j = 0; j < 4; j++)
                    unsafeAtomicAdd(&orow[j*16], gate * (acc[i][j][reg] + vb2[j]));
            }
        }
}

extern "C" void kernel_launch(void* const* d_in, const int* in_sizes, int n_in,
                              void* d_out, int out_size, void* d_ws, size_t ws_size,
                              hipStream_t stream) {
    const float* x  = (const float*)d_in[0];
    const float* Wr = (const float*)d_in[1];
    const float* br = (const float*)d_in[2];
    const float* W1 = (const float*)d_in[3];
    const float* b1 = (const float*)d_in[4];
    const float* W2 = (const float*)d_in[5];
    const float* b2 = (const float*)d_in[6];
    float* out = (float*)d_out;

    char* ws = (char*)d_ws;
    int*   cnt   = (int*)(ws + OFF_CNT);
    float* psum  = (float*)(ws + OFF_PSUM);
    int*   offs  = (int*)(ws + OFF_OFFS);
    int*   rows  = (int*)(ws + OFF_ROWS);
    float* gates = (float*)(ws + OFF_GATES);
    short* xbf   = (short*)(ws + OFF_XBF);
    short* g     = (short*)(ws + OFF_G);
    short* W1s   = (short*)(ws + OFF_W1S);
    short* W2s   = (short*)(ws + OFF_W2S);

    hipMemsetAsync(ws, 0, 192, stream);
    hipMemsetAsync(d_out, 0, (size_t)NTOK * DIM * 4, stream);

    prep_w<<<dim3(32, 32, 8), 256, 0, stream>>>(W1, W1s, 1024, 4096);
    prep_w<<<dim3(64, 8, 8),  256, 0, stream>>>(W2, W2s, 2048, 1024);
    convert_x<<<4096, 256, 0, stream>>>(x, xbf);
    router<<<256, 256, 0, stream>>>(x, Wr, br, cnt, psum, rows, gates);
    finalize_aux<<<1, 64, 0, stream>>>(cnt, psum, offs, out + (size_t)NTOK * DIM);
    gemm1<<<dim3(16, 32, 8), 512, 0, stream>>>(xbf, W1s, b1, cnt, offs, rows, g);
    gemm2<<<dim3(8, 32, 8),  512, 0, stream>>>(g, W2s, b2, cnt, offs, rows, gates, out);
}

// Round 4
// 689.112 us; speedup vs baseline: 1.4329x; 1.0951x over previous
//
#include <hip/hip_runtime.h>
#include <hip/hip_bf16.h>
#include <math.h>

typedef __attribute__((ext_vector_type(8))) __bf16 bh8;   // MFMA A/B frag
typedef __attribute__((ext_vector_type(4))) float  f4;    // MFMA C/D frag

#define NTOK   8192
#define DIM    1024
#define HIDK   2048

// ws layout (bytes)
#define OFF_CNT    0
#define OFF_PSUM   64
#define OFF_OFFS   128
#define OFF_ROWS   512
#define OFF_GATES  (512+262144)
#define OFF_XBF    524800
#define OFF_G      (524800+16777216)          // 16640 x 2048 shorts
#define OFF_W1S    (OFF_G + 68157440)         // 8*4096*1024 shorts (swizzled blobs)
#define OFF_W2S    (OFF_W1S + 67108864)       // 8*1024*2048 shorts

__device__ __forceinline__ unsigned short f2bf(float x){
    union { float f; unsigned u; } v; v.f = x;
    unsigned r = v.u + 0x7FFFu + ((v.u >> 16) & 1u);
    return (unsigned short)(r >> 16);
}
__device__ __forceinline__ unsigned pk2(float a, float b){
    return (unsigned)f2bf(a) | ((unsigned)f2bf(b) << 16);
}
__device__ __forceinline__ void gload_lds16(const void* g, void* l){
    __builtin_amdgcn_global_load_lds((const __attribute__((address_space(1))) void*)g,
                                     (__attribute__((address_space(3))) void*)l, 16, 0, 0);
}

// ---------- x fp32 -> bf16 ----------
__global__ void convert_x(const float* __restrict__ x, short* __restrict__ xbf){
    size_t i = ((size_t)blockIdx.x * 256 + threadIdx.x) * 8;
    const float4* s = (const float4*)(x + i);
    float4 a = s[0], b = s[1];
    uint4 u;
    u.x = pk2(a.x, a.y); u.y = pk2(a.z, a.w);
    u.z = pk2(b.x, b.y); u.w = pk2(b.z, b.w);
    *(uint4*)(xbf + i) = u;
}

// ---------- weights: [e][K][N] fp32 -> swizzled bf16 blobs [e][N/128][K/32][4096 shorts] ----------
// blob slot s (16B) holds col nl=s>>2, k-chunk c = (s&3) ^ (nl&3) ^ ((nl>>2)&3), k = kb*32+c*8+0..7
__global__ void prep_w(const float* __restrict__ W, short* __restrict__ Ws,
                       int Kdim, int Ndim){
    int kb = blockIdx.x, nb = blockIdx.y, e = blockIdx.z;
    int KB = Kdim >> 5, NB = Ndim >> 7;
    __shared__ float tile[32 * 132];   // [k][n], pad 132
    int t = threadIdx.x;
    const float* src = W + ((size_t)(e * Kdim + kb * 32)) * Ndim + (size_t)nb * 128;
    #pragma unroll
    for (int l = 0; l < 4; l++){
        int flat = (l * 256 + t) * 4;
        int k = flat >> 7, n = flat & 127;
        float4 v = *(const float4*)(src + (size_t)k * Ndim + n);
        float* d = &tile[k * 132 + n];
        d[0] = v.x; d[1] = v.y; d[2] = v.z; d[3] = v.w;
    }
    __syncthreads();
    short* dst = Ws + (((size_t)(e * NB + nb)) * KB + kb) * 4096;
    uint out[8];
    #pragma unroll
    for (int sl = 0; sl < 2; sl++){
        int s = t * 2 + sl;
        int nl = s >> 2, pos = s & 3;
        int c = pos ^ (nl & 3) ^ ((nl >> 2) & 3);
        #pragma unroll
        for (int jj = 0; jj < 4; jj++){
            float a = tile[(c * 8 + jj * 2) * 132 + nl];
            float b = tile[(c * 8 + jj * 2 + 1) * 132 + nl];
            out[sl * 4 + jj] = pk2(a, b);
        }
    }
    *(uint4*)(dst + t * 16)     = *(uint4*)&out[0];
    *(uint4*)(dst + t * 16 + 8) = *(uint4*)&out[4];
}

// ---------- router ----------
__global__ void router(const float* __restrict__ x, const float* __restrict__ Wr,
                       const float* __restrict__ br,
                       int* cnt, float* psum, int* rows, float* gates){
    __shared__ float pP[8];
    __shared__ int   tE[32][2];
    __shared__ float tS[32][2];
    __shared__ int   lcnt[8], lpos[64], lexp[64], gbase[8];
    int t = threadIdx.x, lane = t & 63, w = t >> 6;
    if (t < 8){ pP[t] = 0.f; lcnt[t] = 0; }
    __syncthreads();
    int n0 = blockIdx.x * 32 + w * 8;
    for (int tk = 0; tk < 8; tk++){
        int n = n0 + tk;
        float acc[8] = {0,0,0,0,0,0,0,0};
        const float* xr = x + (size_t)n * DIM;
        for (int d = lane; d < DIM; d += 64){
            float xv = xr[d];
            const float* wrow = Wr + d * 8;
            #pragma unroll
            for (int e = 0; e < 8; e++) acc[e] += xv * wrow[e];
        }
        #pragma unroll
        for (int e = 0; e < 8; e++){
            float v = acc[e];
            v += __shfl_xor(v, 32); v += __shfl_xor(v, 16); v += __shfl_xor(v, 8);
            v += __shfl_xor(v, 4);  v += __shfl_xor(v, 2);  v += __shfl_xor(v, 1);
            acc[e] = v;
        }
        if (lane == 0){
            float l[8], ex[8], m = -1e30f;
            #pragma unroll
            for (int e = 0; e < 8; e++){ l[e] = acc[e] + br[e]; m = fmaxf(m, l[e]); }
            float s = 0.f;
            #pragma unroll
            for (int e = 0; e < 8; e++){ ex[e] = expf(l[e] - m); s += ex[e]; }
            float inv = 1.f / s;
            #pragma unroll
            for (int e = 0; e < 8; e++) atomicAdd(&pP[e], ex[e] * inv);
            int i0 = 0; float v0 = l[0];
            #pragma unroll
            for (int e = 1; e < 8; e++) if (l[e] > v0){ v0 = l[e]; i0 = e; }
            int i1 = -1; float v1 = -1e30f;
            #pragma unroll
            for (int e = 0; e < 8; e++) if (e != i0 && l[e] > v1){ v1 = l[e]; i1 = e; }
            float s0 = 1.f / (1.f + expf(v1 - v0));
            int ti = w * 8 + tk;
            tE[ti][0] = i0; tE[ti][1] = i1;
            tS[ti][0] = s0; tS[ti][1] = 1.f - s0;
        }
    }
    __syncthreads();
    if (t < 64){
        int e = tE[t >> 1][t & 1];
        lexp[t] = e;
        lpos[t] = atomicAdd(&lcnt[e], 1);
    }
    __syncthreads();
    if (t < 8){
        gbase[t] = atomicAdd(&cnt[t], lcnt[t]);
        atomicAdd(&psum[t], pP[t]);
    }
    __syncthreads();
    if (t < 64){
        int e = lexp[t];
        int p = gbase[e] + lpos[t];
        int n = blockIdx.x * 32 + (t >> 1);
        rows[e * NTOK + p]  = n;
        gates[e * NTOK + p] = tS[t >> 1][t & 1];
    }
}

__global__ void finalize_aux(const int* cnt, const float* psum, int* offs, float* out_aux){
    if (threadIdx.x == 0){
        int off = 0; float aux = 0.f;
        for (int e = 0; e < 8; e++){
            offs[e] = off; off += cnt[e];
            aux += ((float)cnt[e] * (1.f/8192.f)) * (psum[e] * (1.f/8192.f));
        }
        out_aux[0] = 8.f * aux;
    }
}

// ---------- GEMM1: 128 rows x 64 g-cols (64 a-cols + 64 b-cols), 256 thr, 4 waves ----------
// wave = 64 rows x 32 g-cols; acc 16 f4 = 64 AGPR. 16 MFMA : 8 ds_read_b128 per iter.
__global__ __launch_bounds__(256) void gemm1(
    const short* __restrict__ xbf, const short* __restrict__ W1s,
    const float* __restrict__ b1, const int* __restrict__ cnt,
    const int* __restrict__ offs, const int* __restrict__ rows,
    short* __restrict__ g)
{
    int e = blockIdx.z;
    int Me = cnt[e];
    int mbase = blockIdx.y << 7;
    if (mbase >= Me) return;
    int xB = blockIdx.x;                 // 0..31 -> g-cols xB*64
    __shared__ short As[128 * 32];       // 8KB
    __shared__ short Bsa[64 * 32];       // 4KB
    __shared__ short Bsb[64 * 32];       // 4KB

    int t = threadIdx.x, lane = t & 63, w = t >> 6;
    int wr = w & 1, wc = w >> 1;
    int m = lane & 15, q = lane >> 4;
    int sw8 = (q ^ (m & 3) ^ ((m >> 2) & 3)) << 3;

    const int* rowsE = rows + (e << 13) + mbase;
    int r = t >> 2, pos = t & 3;
    int ca = pos ^ (r & 3) ^ ((r >> 2) & 3);
    int tok0 = (mbase + r      < Me) ? rowsE[r]      : 0;
    int tok1 = (mbase + r + 64 < Me) ? rowsE[r + 64] : 0;
    const short* ga0 = xbf + ((size_t)tok0 << 10) + (ca << 3);
    const short* ga1 = xbf + ((size_t)tok1 << 10) + (ca << 3);
    int ha = xB & 1, nb128 = xB >> 1;
    const short* gb0 = W1s + ((size_t)((e * 32 + nb128)      * 32)) * 4096 + (ha * 256 + t) * 8;
    const short* gb1 = W1s + ((size_t)((e * 32 + 16 + nb128) * 32)) * 4096 + (ha * 256 + t) * 8;
    short* ldsA0 = As  + w * 512;            // slots w*64..w*64+63 (rows 0..63)
    short* ldsA1 = As  + 2048 + w * 512;     // rows 64..127
    short* ldsBa = Bsa + w * 512;
    short* ldsBb = Bsb + w * 512;

    f4 acc_a[4][2], acc_b[4][2];
    f4 zz = {0.f,0.f,0.f,0.f};
    #pragma unroll
    for (int i = 0; i < 4; i++)
        #pragma unroll
        for (int j = 0; j < 2; j++){ acc_a[i][j] = zz; acc_b[i][j] = zz; }

    for (int k0 = 0; k0 < DIM; k0 += 32){
        __syncthreads();
        gload_lds16(ga0, ldsA0);
        gload_lds16(ga1, ldsA1);
        gload_lds16(gb0, ldsBa);
        gload_lds16(gb1, ldsBb);
        ga0 += 32; ga1 += 32; gb0 += 4096; gb1 += 4096;
        __syncthreads();
        bh8 av[4], ba[2], bb[2];
        #pragma unroll
        for (int i = 0; i < 4; i++)
            av[i] = *(const bh8*)&As[(wr*64 + i*16 + m) * 32 + sw8];
        #pragma unroll
        for (int j = 0; j < 2; j++){
            int nn = ((wc << 5) + j*16 + m) * 32 + sw8;
            ba[j] = *(const bh8*)&Bsa[nn];
            bb[j] = *(const bh8*)&Bsb[nn];
        }
        #pragma unroll
        for (int i = 0; i < 4; i++)
            #pragma unroll
            for (int j = 0; j < 2; j++){
                acc_a[i][j] = __builtin_amdgcn_mfma_f32_16x16x32_bf16(av[i], ba[j], acc_a[i][j], 0, 0, 0);
                acc_b[i][j] = __builtin_amdgcn_mfma_f32_16x16x32_bf16(av[i], bb[j], acc_b[i][j], 0, 0, 0);
            }
    }
    int c0 = xB << 6;
    const float* b1e = b1 + (e << 12);
    int colb = (wc << 5) + m;
    float vba[2], vbb[2];
    #pragma unroll
    for (int j = 0; j < 2; j++){
        vba[j] = b1e[c0 + colb + j*16];
        vbb[j] = b1e[HIDK + c0 + colb + j*16];
    }
    int rb = wr * 64 + (q << 2);
    short* gE = g + ((size_t)(offs[e] + mbase)) * HIDK;
    #pragma unroll
    for (int i = 0; i < 4; i++)
        #pragma unroll
        for (int reg = 0; reg < 4; reg++){
            int mr = rb + i*16 + reg;
            if (mbase + mr < Me){
                short* grow = gE + (size_t)mr * HIDK + c0 + colb;
                #pragma unroll
                for (int j = 0; j < 2; j++){
                    float va = acc_a[i][j][reg] + vba[j];
                    float vb = acc_b[i][j][reg] + vbb[j];
                    grow[j*16] = (short)f2bf(va / (1.f + __expf(-va)) * vb);
                }
            }
        }
}

// ---------- GEMM2: 128 rows x 128 out-cols, 256 thr, 4 waves (wave 64x64) ----------
__global__ __launch_bounds__(256) void gemm2(
    const short* __restrict__ g, const short* __restrict__ W2s,
    const float* __restrict__ b2, const int* __restrict__ cnt,
    const int* __restrict__ offs, const int* __restrict__ rows,
    const float* __restrict__ gates, float* __restrict__ out)
{
    int e = blockIdx.z;
    int Me = cnt[e];
    int mbase = blockIdx.y << 7;
    if (mbase >= Me) return;
    int db = blockIdx.x;                 // 0..7
    __shared__ short As[128 * 32];       // 8KB
    __shared__ short Bs[128 * 32];       // 8KB

    int t = threadIdx.x, lane = t & 63, w = t >> 6;
    int wr = w & 1, wc = w >> 1;
    int m = lane & 15, q = lane >> 4;
    int sw8 = (q ^ (m & 3) ^ ((m >> 2) & 3)) << 3;

    int gbaseR = offs[e] + mbase;
    int r = t >> 2;
    int ca = (t & 3) ^ (r & 3) ^ ((r >> 2) & 3);
    const short* ga0 = g + ((size_t)(gbaseR + r))      * HIDK + (ca << 3);
    const short* ga1 = g + ((size_t)(gbaseR + r + 64)) * HIDK + (ca << 3);
    const short* gb0 = W2s + ((size_t)((e * 8 + db) * 64)) * 4096 + t * 8;
    const short* gb1 = gb0 + 2048;       // slots 256..511 (cols 64..127)
    short* ldsA0 = As + w * 512;
    short* ldsA1 = As + 2048 + w * 512;
    short* ldsB0 = Bs + w * 512;
    short* ldsB1 = Bs + 2048 + w * 512;

    f4 acc[4][4];
    f4 zz = {0.f,0.f,0.f,0.f};
    #pragma unroll
    for (int i = 0; i < 4; i++)
        #pragma unroll
        for (int j = 0; j < 4; j++) acc[i][j] = zz;

    for (int k0 = 0; k0 < HIDK; k0 += 32){
        __syncthreads();
        gload_lds16(ga0, ldsA0);
        gload_lds16(ga1, ldsA1);
        gload_lds16(gb0, ldsB0);
        gload_lds16(gb1, ldsB1);
        ga0 += 32; ga1 += 32; gb0 += 4096; gb1 += 4096;
        __syncthreads();
        bh8 av[4], bv[4];
        #pragma unroll
        for (int i = 0; i < 4; i++)
            av[i] = *(const bh8*)&As[(wr*64 + i*16 + m) * 32 + sw8];
        #pragma unroll
        for (int j = 0; j < 4; j++)
            bv[j] = *(const bh8*)&Bs[(wc*64 + j*16 + m) * 32 + sw8];
        #pragma unroll
        for (int i = 0; i < 4; i++)
            #pragma unroll
            for (int j = 0; j < 4; j++)
                acc[i][j] = __builtin_amdgcn_mfma_f32_16x16x32_bf16(av[i], bv[j], acc[i][j], 0, 0, 0);
    }
    int d0 = db << 7;
    const float* b2e = b2 + (e << 10);
    int colb = wc * 64 + m;
    float vb2[4];
    #pragma unroll
    for (int j = 0; j < 4; j++) vb2[j] = b2e[d0 + colb + j*16];
    const int* rowsE = rows + (e << 13) + mbase;
    const float* gatesE = gates + (e << 13) + mbase;
    int rb = wr * 64 + (q << 2);
    #pragma unroll
    for (int i = 0; i < 4; i++)
        #pragma unroll
        for (int reg = 0; reg < 4; reg++){
            int mr = rb + i*16 + reg;
            if (mbase + mr < Me){
                int token = rowsE[mr];
                float gate = gatesE[mr];
                float* orow = out + ((size_t)token << 10) + d0 + colb;
                #pragma unroll
                for (int j = 0; j < 4; j++)
                    unsafeAtomicAdd(&orow[j*16], gate * (acc[i][j][reg] + vb2[j]));
            }
        }
}

extern "C" void kernel_launch(void* const* d_in, const int* in_sizes, int n_in,
                              void* d_out, int out_size, void* d_ws, size_t ws_size,
                              hipStream_t stream) {
    const float* x  = (const float*)d_in[0];
    const float* Wr = (const float*)d_in[1];
    const float* br = (const float*)d_in[2];
    const float* W1 = (const float*)d_in[3];
    const float* b1 = (const float*)d_in[4];
    const float* W2 = (const float*)d_in[5];
    const float* b2 = (const float*)d_in[6];
    float* out = (float*)d_out;

    char* ws = (char*)d_ws;
    int*   cnt   = (int*)(ws + OFF_CNT);
    float* psum  = (float*)(ws + OFF_PSUM);
    int*   offs  = (int*)(ws + OFF_OFFS);
    int*   rows  = (int*)(ws + OFF_ROWS);
    float* gates = (float*)(ws + OFF_GATES);
    short* xbf   = (short*)(ws + OFF_XBF);
    short* g     = (short*)(ws + OFF_G);
    short* W1s   = (short*)(ws + OFF_W1S);
    short* W2s   = (short*)(ws + OFF_W2S);

    hipMemsetAsync(ws, 0, 192, stream);
    hipMemsetAsync(d_out, 0, (size_t)NTOK * DIM * 4, stream);

    prep_w<<<dim3(32, 32, 8), 256, 0, stream>>>(W1, W1s, 1024, 4096);
    prep_w<<<dim3(64, 8, 8),  256, 0, stream>>>(W2, W2s, 2048, 1024);
    convert_x<<<4096, 256, 0, stream>>>(x, xbf);
    router<<<256, 256, 0, stream>>>(x, Wr, br, cnt, psum, rows, gates);
    finalize_aux<<<1, 64, 0, stream>>>(cnt, psum, offs, out + (size_t)NTOK * DIM);
    gemm1<<<dim3(32, 64, 8), 256, 0, stream>>>(xbf, W1s, b1, cnt, offs, rows, g);
    gemm2<<<dim3(8, 64, 8),  256, 0, stream>>>(g, W2s, b2, cnt, offs, rows, gates, out);
}